// Round 6
// baseline (1805.905 us; speedup 1.0000x reference)
//
#include <hip/hip_runtime.h>

namespace {

constexpr int C  = 64;    // input channels
constexpr int H  = 448;   // rows (= conv groups)
constexpr int Wd = 608;   // width
constexpr int K  = 32;    // stage-1 classes
constexpr int B  = 2;     // batch
constexpr int TW = 256;   // pixels per block tile
constexpr int NTILE = 3;             // ceil(608/256)
constexpr int NBLK  = B * H * NTILE; // 2688, % 8 == 0 -> bijective XCD swizzle

constexpr size_t W2T_BYTES = (size_t)H * C * C * sizeof(float);  // 7.3 MB

__device__ __forceinline__ float lrelu(float v) {
    return v >= 0.0f ? v : 0.01f * v;
}

// One-shot 64x64 transpose per h: W2T[h][c][o] = W2[h][o][c].
__global__ __launch_bounds__(256)
void transpose_w2(const float* __restrict__ W2, float* __restrict__ W2T) {
    __shared__ float t[C][C + 1];
    const int h = blockIdx.x;
    const float* __restrict__ in  = W2  + (size_t)h * C * C;
    float* __restrict__       op  = W2T + (size_t)h * C * C;
    const int tid = threadIdx.x;
#pragma unroll
    for (int k = 0; k < (C * C) / 256; ++k) {
        const int idx = tid + k * 256;
        t[idx >> 6][idx & 63] = in[idx];
    }
    __syncthreads();
#pragma unroll
    for (int k = 0; k < (C * C) / 256; ++k) {
        const int idx = tid + k * 256;
        op[idx] = t[idx & 63][idx >> 6];
    }
}

// Fused pipeline, one pixel per thread. Weights staged in LDS (exactly
// 40960 B = 160/4 -> 4 blocks/CU, 16 waves). Biases deliberately NOT
// staged: b1 is one uniform s_load per c-iter (hidden under 128 FMAs),
// b3 is 32 hoistable uniform scalars.
template <bool USE_WT>
__global__ __launch_bounds__(256, 4)
void reg1stage_kernel(const float* __restrict__ x,
                      const float* __restrict__ W1, const float* __restrict__ b1,
                      const float* __restrict__ W2orT, const float* __restrict__ b2,
                      const float* __restrict__ W3, const float* __restrict__ b3,
                      const float* __restrict__ Wr, const float* __restrict__ br,
                      float* __restrict__ out)
{
    __shared__ float sW1[C * C];   // 16 KB
    __shared__ float sW2[C * C];   // 16 KB (transposed if USE_WT)
    __shared__ float sW3[K * C];   //  8 KB   -> total 40960 B exactly

    const int tid = threadIdx.x;

    // XCD-aware swizzle: consecutive h on one XCD -> per-XCD weight
    // footprint ~3.2 MB < 4 MB L2. Bijective (2688 % 8 == 0).
    const int wg  = blockIdx.x;
    const int swz = (wg & 7) * (NBLK / 8) + (wg >> 3);
    const int h    = swz / 6;            // 6 blocks per h: 2 batches x 3 tiles
    const int rem  = swz - 6 * h;
    const int b    = rem / 3;
    const int tile = rem - 3 * (rem / 3);
    const int w    = tile * TW + tid;
    const bool valid = (w < Wd);
    const int wc   = valid ? w : (Wd - 1);   // clamp; no early return (barrier)

    const size_t HW = (size_t)H * Wd;
    const float* __restrict__ xcol = x + ((size_t)b * C * H + (size_t)h) * Wd + wc;
    const float* __restrict__ W1h  = W1    + (size_t)h * C * C;
    const float* __restrict__ W2h  = W2orT + (size_t)h * C * C;
    const float* __restrict__ W3h  = W3    + (size_t)h * K * C;
    const float* __restrict__ b1h  = b1 + (size_t)h * C;
    const float* __restrict__ b2h  = b2 + (size_t)h * C;
    const float* __restrict__ b3h  = b3 + (size_t)h * K;

    // ---- stage weights: coalesced float4 copies (one-time, L2-hot) ----
    {
        const float4* __restrict__ g1 = reinterpret_cast<const float4*>(W1h);
        const float4* __restrict__ g2 = reinterpret_cast<const float4*>(W2h);
        const float4* __restrict__ g3 = reinterpret_cast<const float4*>(W3h);
        float4* s1 = reinterpret_cast<float4*>(sW1);
        float4* s2 = reinterpret_cast<float4*>(sW2);
        float4* s3 = reinterpret_cast<float4*>(sW3);
#pragma unroll
        for (int r = 0; r < 4; ++r) s1[tid + 256 * r] = g1[tid + 256 * r];
#pragma unroll
        for (int r = 0; r < 4; ++r) s2[tid + 256 * r] = g2[tid + 256 * r];
#pragma unroll
        for (int r = 0; r < 2; ++r) s3[tid + 256 * r] = g3[tid + 256 * r];
    }

    // ---- x loaded from HBM exactly once; stays in registers ----
    float xv[C];
#pragma unroll
    for (int c = 0; c < C; ++c) xv[c] = xcol[(size_t)c * HW];

    // ---- a2 accumulators seeded with b2 (one-time uniform loads) ----
    float a2[C];
#pragma unroll
    for (int o = 0; o < C; ++o) a2[o] = b2h[o];

    __syncthreads();   // staging complete

    // ---- fused layers 1+2, c-outer; a1_c is a scalar ----
#pragma unroll 2
    for (int c = 0; c < C; ++c) {
        float p0 = 0.0f, p1 = 0.0f, p2 = 0.0f, p3 = 0.0f;
#pragma unroll
        for (int i = 0; i < C / 4; ++i) {
            const float4 wv = *reinterpret_cast<const float4*>(&sW1[c * C + 4 * i]);
            p0 = fmaf(wv.x, xv[4 * i + 0], p0);
            p1 = fmaf(wv.y, xv[4 * i + 1], p1);
            p2 = fmaf(wv.z, xv[4 * i + 2], p2);
            p3 = fmaf(wv.w, xv[4 * i + 3], p3);
        }
        const float a1c = lrelu(b1h[c] + ((p0 + p1) + (p2 + p3)));

        if constexpr (USE_WT) {
            // a2[o] += W2T[c][o] * a1c  (64 independent updates)
#pragma unroll
            for (int i = 0; i < C / 4; ++i) {
                const float4 wv = *reinterpret_cast<const float4*>(&sW2[c * C + 4 * i]);
                a2[4 * i + 0] = fmaf(wv.x, a1c, a2[4 * i + 0]);
                a2[4 * i + 1] = fmaf(wv.y, a1c, a2[4 * i + 1]);
                a2[4 * i + 2] = fmaf(wv.z, a1c, a2[4 * i + 2]);
                a2[4 * i + 3] = fmaf(wv.w, a1c, a2[4 * i + 3]);
            }
        } else {
            // fallback: column reads on untransposed W2 (uniform b32 broadcasts)
#pragma unroll
            for (int o = 0; o < C; ++o)
                a2[o] = fmaf(sW2[o * C + c], a1c, a2[o]);
        }
    }
#pragma unroll
    for (int o = 0; o < C; ++o) a2[o] = lrelu(a2[o]);

    // ---- layer 3 + argmax, k-tiles of 8 (lrelu monotone -> skip it) ----
    float best = -3.402823466e38f;
    int   bi   = 0;
#pragma unroll 1
    for (int kt = 0; kt < K / 8; ++kt) {
        float s[8];
#pragma unroll
        for (int j = 0; j < 8; ++j) s[j] = b3h[kt * 8 + j];   // uniform, hoistable
#pragma unroll
        for (int i = 0; i < C / 4; ++i) {
#pragma unroll
            for (int j = 0; j < 8; ++j) {
                const float4 wv =
                    *reinterpret_cast<const float4*>(&sW3[(kt * 8 + j) * C + 4 * i]);
                s[j] = fmaf(wv.x, a2[4 * i + 0], s[j]);
                s[j] = fmaf(wv.y, a2[4 * i + 1], s[j]);
                s[j] = fmaf(wv.z, a2[4 * i + 2], s[j]);
                s[j] = fmaf(wv.w, a2[4 * i + 3], s[j]);
            }
        }
#pragma unroll
        for (int j = 0; j < 8; ++j) {
            if (s[j] > best) { best = s[j]; bi = kt * 8 + j; }  // first max
        }
    }

    // ---- conditional regression straight from register-resident x ----
    const int flat = h * K + bi;
    const float4* __restrict__ wr4 =
        reinterpret_cast<const float4*>(Wr + (size_t)flat * C * 2);
    float f0 = 0.0f, f1 = 0.0f;
#pragma unroll
    for (int c2 = 0; c2 < C / 2; ++c2) {
        const float4 wv = wr4[c2];   // per-lane gather; L2-hot after swizzle
        f0 = fmaf(xv[2 * c2 + 0], wv.x, f0);
        f1 = fmaf(xv[2 * c2 + 0], wv.y, f1);
        f0 = fmaf(xv[2 * c2 + 1], wv.z, f0);
        f1 = fmaf(xv[2 * c2 + 1], wv.w, f1);
    }
    const float r0 = lrelu(f0 + br[2 * flat + 0]);
    const float r1 = lrelu(f1 + br[2 * flat + 1]);
    const float xpos = ((float)flat + r0) * (1.0f / K);
    const float mask = lrelu(r1);

    if (valid) {
        const size_t opix = ((size_t)b * H + h) * Wd + w;
        out[opix] = xpos;
        out[(size_t)B * H * Wd + opix] = mask;
    }
}

} // namespace

extern "C" void kernel_launch(void* const* d_in, const int* in_sizes, int n_in,
                              void* d_out, int out_size, void* d_ws, size_t ws_size,
                              hipStream_t stream) {
    const float* x  = (const float*)d_in[0];
    const float* W1 = (const float*)d_in[1];
    const float* b1 = (const float*)d_in[2];
    const float* W2 = (const float*)d_in[3];
    const float* b2 = (const float*)d_in[4];
    const float* W3 = (const float*)d_in[5];
    const float* b3 = (const float*)d_in[6];
    const float* Wr = (const float*)d_in[7];
    const float* br = (const float*)d_in[8];
    float* out = (float*)d_out;

    dim3 grid(NBLK);
    dim3 block(TW);

    if (ws_size >= W2T_BYTES) {
        float* W2T = (float*)d_ws;
        hipLaunchKernelGGL(transpose_w2, dim3(H), dim3(256), 0, stream, W2, W2T);
        hipLaunchKernelGGL((reg1stage_kernel<true>), grid, block, 0, stream,
                           x, W1, b1, W2T, b2, W3, b3, Wr, br, out);
    } else {
        hipLaunchKernelGGL((reg1stage_kernel<false>), grid, block, 0, stream,
                           x, W1, b1, W2, b2, W3, b3, Wr, br, out);
    }
}

// Round 7
// 358.540 us; speedup vs baseline: 5.0368x; 5.0368x over previous
//
#include <hip/hip_runtime.h>

namespace {

constexpr int C   = 64;    // input channels
constexpr int H   = 448;   // rows (= conv groups)
constexpr int Wd  = 608;   // width
constexpr int K   = 32;    // stage-1 classes
constexpr int B   = 2;     // batch
constexpr int PIX = 128;   // w-columns per block (256 thr = 32 cols x 2 halves x 4 waves)
constexpr int NTILE = 5;            // ceil(608/128)
constexpr int NBLK  = H * NTILE;    // 2240, % 8 == 0 -> bijective XCD swizzle

constexpr size_t W2T_BYTES = (size_t)H * C * C * sizeof(float);  // 7.3 MB

__device__ __forceinline__ float lrelu(float v) {
    return v >= 0.0f ? v : 0.01f * v;
}

// One-shot 64x64 transpose per h: W2T[h][c][o] = W2[h][o][c].
__global__ __launch_bounds__(256)
void transpose_w2(const float* __restrict__ W2, float* __restrict__ W2T) {
    __shared__ float t[C][C + 1];
    const int h = blockIdx.x;
    const float* __restrict__ in  = W2  + (size_t)h * C * C;
    float* __restrict__       op  = W2T + (size_t)h * C * C;
    const int tid = threadIdx.x;
#pragma unroll
    for (int k = 0; k < (C * C) / 256; ++k) {
        const int idx = tid + k * 256;
        t[idx >> 6][idx & 63] = in[idx];
    }
    __syncthreads();
#pragma unroll
    for (int k = 0; k < (C * C) / 256; ++k) {
        const int idx = tid + k * 256;
        op[idx] = t[idx & 63][idx >> 6];
    }
}

// Thread = (w-column, channel-half), both batches. Each LDS weight read
// serves 2 pixels (b=0,1) -> LDS return-BW per pixel halved vs 1-pixel/
// thread. Cross-half partial sums combined with shfl_xor(32); biases
// added AFTER the combine. State: 4x32 floats -> no spill at (256,3).
template <bool USE_WT>
__global__ __launch_bounds__(256, 3)
void reg1stage_kernel(const float* __restrict__ x,
                      const float* __restrict__ W1, const float* __restrict__ b1,
                      const float* __restrict__ W2orT, const float* __restrict__ b2,
                      const float* __restrict__ W3, const float* __restrict__ b3,
                      const float* __restrict__ Wr, const float* __restrict__ br,
                      float* __restrict__ out)
{
    __shared__ float sW1[C * C];   // 16 KB
    __shared__ float sW2[C * C];   // 16 KB (transposed if USE_WT)
    __shared__ float sW3[K * C];   //  8 KB   -> 40960 B total

    const int tid = threadIdx.x;

    // XCD swizzle: 280 consecutive blocks (56 h values, ~3.2 MB weights) per XCD.
    const int wg   = blockIdx.x;
    const int swz  = (wg & 7) * (NBLK / 8) + (wg >> 3);
    const int h    = swz / NTILE;
    const int tile = swz - NTILE * h;

    const int wave = tid >> 6;         // 4 waves/block
    const int lane = tid & 63;
    const int col  = lane & 31;        // w-column within wave
    const int half = lane >> 5;        // channel half: 0 -> [0,32), 1 -> [32,64)
    const int cb   = half * 32;
    const int w    = tile * PIX + wave * 32 + col;
    const bool valid = (w < Wd);
    const int wc   = valid ? w : (Wd - 1);   // clamp; no early return (barrier)

    const size_t HW = (size_t)H * Wd;
    const float* __restrict__ W1h = W1    + (size_t)h * C * C;
    const float* __restrict__ W2h = W2orT + (size_t)h * C * C;
    const float* __restrict__ W3h = W3    + (size_t)h * K * C;
    const float* __restrict__ b1h = b1 + (size_t)h * C;
    const float* __restrict__ b2h = b2 + (size_t)h * C;
    const float* __restrict__ b3h = b3 + (size_t)h * K;

    // ---- stage weights: coalesced float4 copies (one-time, L2/L3-hot) ----
    {
        const float4* __restrict__ g1 = reinterpret_cast<const float4*>(W1h);
        const float4* __restrict__ g2 = reinterpret_cast<const float4*>(W2h);
        const float4* __restrict__ g3 = reinterpret_cast<const float4*>(W3h);
        float4* s1 = reinterpret_cast<float4*>(sW1);
        float4* s2 = reinterpret_cast<float4*>(sW2);
        float4* s3 = reinterpret_cast<float4*>(sW3);
#pragma unroll
        for (int r = 0; r < 4; ++r) s1[tid + 256 * r] = g1[tid + 256 * r];
#pragma unroll
        for (int r = 0; r < 4; ++r) s2[tid + 256 * r] = g2[tid + 256 * r];
#pragma unroll
        for (int r = 0; r < 2; ++r) s3[tid + 256 * r] = g3[tid + 256 * r];
    }

    // ---- x: this lane's channel-half, both batches (HBM once) ----
    float xv0[32], xv1[32];
    {
        const float* __restrict__ x0 = x + (((size_t)0 * C + cb) * H + h) * Wd + wc;
        const float* __restrict__ x1 = x + (((size_t)1 * C + cb) * H + h) * Wd + wc;
#pragma unroll
        for (int c = 0; c < 32; ++c) {
            xv0[c] = x0[(size_t)c * HW];
            xv1[c] = x1[(size_t)c * HW];
        }
    }

    // ---- a2 accumulators (own output half), seeded with b2 ----
    float a20[32], a21[32];
    {
        const float4* __restrict__ bv = reinterpret_cast<const float4*>(b2h + cb);
#pragma unroll
        for (int i = 0; i < 8; ++i) {
            const float4 t = bv[i];
            a20[4*i+0] = t.x; a20[4*i+1] = t.y; a20[4*i+2] = t.z; a20[4*i+3] = t.w;
            a21[4*i+0] = t.x; a21[4*i+1] = t.y; a21[4*i+2] = t.z; a21[4*i+3] = t.w;
        }
    }

    __syncthreads();   // staging complete

    // ---- fused layers 1+2, c-outer; half-dot + shfl combine ----
#pragma unroll 1
    for (int c = 0; c < C; ++c) {
        float p0 = 0.0f, q0 = 0.0f, p1 = 0.0f, q1 = 0.0f;
#pragma unroll
        for (int i = 0; i < 8; ++i) {
            const float4 wv = *reinterpret_cast<const float4*>(&sW1[c * C + cb + 4 * i]);
            p0 = fmaf(wv.x, xv0[4*i+0], p0);
            q0 = fmaf(wv.y, xv0[4*i+1], q0);
            p0 = fmaf(wv.z, xv0[4*i+2], p0);
            q0 = fmaf(wv.w, xv0[4*i+3], q0);
            p1 = fmaf(wv.x, xv1[4*i+0], p1);
            q1 = fmaf(wv.y, xv1[4*i+1], q1);
            p1 = fmaf(wv.z, xv1[4*i+2], p1);
            q1 = fmaf(wv.w, xv1[4*i+3], q1);
        }
        float s0 = p0 + q0;
        float s1 = p1 + q1;
        s0 += __shfl_xor(s0, 32);          // + partner half's partial
        s1 += __shfl_xor(s1, 32);
        const float b1c  = b1h[c];          // uniform s_load, 1 per 128 FMAs
        const float a1c0 = lrelu(b1c + s0);
        const float a1c1 = lrelu(b1c + s1);

        if constexpr (USE_WT) {
#pragma unroll
            for (int i = 0; i < 8; ++i) {
                const float4 wv = *reinterpret_cast<const float4*>(&sW2[c * C + cb + 4 * i]);
                a20[4*i+0] = fmaf(wv.x, a1c0, a20[4*i+0]);
                a20[4*i+1] = fmaf(wv.y, a1c0, a20[4*i+1]);
                a20[4*i+2] = fmaf(wv.z, a1c0, a20[4*i+2]);
                a20[4*i+3] = fmaf(wv.w, a1c0, a20[4*i+3]);
                a21[4*i+0] = fmaf(wv.x, a1c1, a21[4*i+0]);
                a21[4*i+1] = fmaf(wv.y, a1c1, a21[4*i+1]);
                a21[4*i+2] = fmaf(wv.z, a1c1, a21[4*i+2]);
                a21[4*i+3] = fmaf(wv.w, a1c1, a21[4*i+3]);
            }
        } else {
            // fallback: column reads on untransposed W2
#pragma unroll
            for (int o = 0; o < 32; ++o) {
                const float wv = sW2[(cb + o) * C + c];
                a20[o] = fmaf(wv, a1c0, a20[o]);
                a21[o] = fmaf(wv, a1c1, a21[o]);
            }
        }
    }
#pragma unroll
    for (int o = 0; o < 32; ++o) { a20[o] = lrelu(a20[o]); a21[o] = lrelu(a21[o]); }

    // ---- layer 3 + argmax, k-tiles of 4; bias added after combine ----
    float best0 = -3.402823466e38f, best1 = -3.402823466e38f;
    int   bi0 = 0, bi1 = 0;
#pragma unroll 1
    for (int kt = 0; kt < K / 4; ++kt) {
        float s0[4] = {0,0,0,0};
        float s1[4] = {0,0,0,0};
#pragma unroll
        for (int i = 0; i < 8; ++i) {
#pragma unroll
            for (int j = 0; j < 4; ++j) {
                const float4 wv =
                    *reinterpret_cast<const float4*>(&sW3[(kt*4 + j) * C + cb + 4 * i]);
                s0[j] = fmaf(wv.x, a20[4*i+0], s0[j]);
                s0[j] = fmaf(wv.y, a20[4*i+1], s0[j]);
                s0[j] = fmaf(wv.z, a20[4*i+2], s0[j]);
                s0[j] = fmaf(wv.w, a20[4*i+3], s0[j]);
                s1[j] = fmaf(wv.x, a21[4*i+0], s1[j]);
                s1[j] = fmaf(wv.y, a21[4*i+1], s1[j]);
                s1[j] = fmaf(wv.z, a21[4*i+2], s1[j]);
                s1[j] = fmaf(wv.w, a21[4*i+3], s1[j]);
            }
        }
#pragma unroll
        for (int j = 0; j < 4; ++j) {
            const float bj = b3h[kt*4 + j];                  // uniform
            const float t0 = s0[j] + __shfl_xor(s0[j], 32) + bj;  // commutative add:
            const float t1 = s1[j] + __shfl_xor(s1[j], 32) + bj;  // both halves identical
            if (t0 > best0) { best0 = t0; bi0 = kt*4 + j; }  // strict > = first max
            if (t1 > best1) { best1 = t1; bi1 = kt*4 + j; }
        }
    }

    // ---- conditional regression from register-resident x halves ----
    const int flat0 = h * K + bi0;
    const int flat1 = h * K + bi1;
    const float4* __restrict__ wr0 =
        reinterpret_cast<const float4*>(Wr + (size_t)flat0 * C * 2) + (cb >> 1);
    const float4* __restrict__ wr1 =
        reinterpret_cast<const float4*>(Wr + (size_t)flat1 * C * 2) + (cb >> 1);
    float f00 = 0.0f, f01 = 0.0f, f10 = 0.0f, f11 = 0.0f;
#pragma unroll
    for (int j = 0; j < 16; ++j) {       // 32 channels of this half, 2 per float4
        const float4 w0 = wr0[j];
        f00 = fmaf(xv0[2*j+0], w0.x, f00);
        f01 = fmaf(xv0[2*j+0], w0.y, f01);
        f00 = fmaf(xv0[2*j+1], w0.z, f00);
        f01 = fmaf(xv0[2*j+1], w0.w, f01);
        const float4 w1 = wr1[j];
        f10 = fmaf(xv1[2*j+0], w1.x, f10);
        f11 = fmaf(xv1[2*j+0], w1.y, f11);
        f10 = fmaf(xv1[2*j+1], w1.z, f10);
        f11 = fmaf(xv1[2*j+1], w1.w, f11);
    }
    f00 += __shfl_xor(f00, 32);
    f01 += __shfl_xor(f01, 32);
    f10 += __shfl_xor(f10, 32);
    f11 += __shfl_xor(f11, 32);

    const float r00 = lrelu(f00 + br[2 * flat0 + 0]);
    const float r01 = lrelu(f01 + br[2 * flat0 + 1]);
    const float r10 = lrelu(f10 + br[2 * flat1 + 0]);
    const float r11 = lrelu(f11 + br[2 * flat1 + 1]);

    if (valid && half == 0) {
        const size_t HWall = (size_t)B * H * Wd;
        const size_t o0 = ((size_t)0 * H + h) * Wd + w;
        const size_t o1 = ((size_t)1 * H + h) * Wd + w;
        out[o0]         = ((float)flat0 + r00) * (1.0f / K);
        out[o1]         = ((float)flat1 + r10) * (1.0f / K);
        out[HWall + o0] = lrelu(r01);     // double lrelu, per reference
        out[HWall + o1] = lrelu(r11);
    }
}

} // namespace

extern "C" void kernel_launch(void* const* d_in, const int* in_sizes, int n_in,
                              void* d_out, int out_size, void* d_ws, size_t ws_size,
                              hipStream_t stream) {
    const float* x  = (const float*)d_in[0];
    const float* W1 = (const float*)d_in[1];
    const float* b1 = (const float*)d_in[2];
    const float* W2 = (const float*)d_in[3];
    const float* b2 = (const float*)d_in[4];
    const float* W3 = (const float*)d_in[5];
    const float* b3 = (const float*)d_in[6];
    const float* Wr = (const float*)d_in[7];
    const float* br = (const float*)d_in[8];
    float* out = (float*)d_out;

    dim3 grid(NBLK);
    dim3 block(256);

    if (ws_size >= W2T_BYTES) {
        float* W2T = (float*)d_ws;
        hipLaunchKernelGGL(transpose_w2, dim3(H), dim3(256), 0, stream, W2, W2T);
        hipLaunchKernelGGL((reg1stage_kernel<true>), grid, block, 0, stream,
                           x, W1, b1, W2T, b2, W3, b3, Wr, br, out);
    } else {
        hipLaunchKernelGGL((reg1stage_kernel<false>), grid, block, 0, stream,
                           x, W1, b1, W2, b2, W3, b3, Wr, br, out);
    }
}